// Round 11
// baseline (368.899 us; speedup 1.0000x reference)
//
#include <hip/hip_runtime.h>
#include <stdint.h>

// Problem constants
#define M_TOT 8192      // B*N = 4*2048 rows
#define N_TOT 16384     // out_dim = 2*128*64
#define K_TOT 1024      // HIDDEN

typedef __bf16 bf16x8 __attribute__((ext_vector_type(8)));
typedef float f32x4 __attribute__((ext_vector_type(4)));

__device__ __forceinline__ unsigned short f2bf(float f) {
  unsigned int u = __float_as_uint(f);
  u = u + 0x7FFFu + ((u >> 16) & 1u);   // RNE
  return (unsigned short)(u >> 16);
}

__device__ __forceinline__ void gload_lds16(const void* g, void* l) {
  __builtin_amdgcn_global_load_lds(
      (const __attribute__((address_space(1))) unsigned int*)g,
      (__attribute__((address_space(3))) unsigned int*)l,
      16, 0, 0);
}

// ---- prep kernel 1: node f32 -> bf16, 32 elems/thread, 1024 blocks ----
__global__ __launch_bounds__(256) void k_convert_node(
    const float* __restrict__ src, unsigned short* __restrict__ dst) {
  size_t base = ((size_t)blockIdx.x * 256 + threadIdx.x) * 8;
#pragma unroll
  for (int it = 0; it < 4; it++) {
    size_t i = base + (size_t)it * (1024 * 256 * 8);
    float4 v0 = *(const float4*)(src + i);
    float4 v1 = *(const float4*)(src + i + 4);
    union { unsigned short u[8]; uint4 q; } r;
    r.u[0] = f2bf(v0.x); r.u[1] = f2bf(v0.y); r.u[2] = f2bf(v0.z); r.u[3] = f2bf(v0.w);
    r.u[4] = f2bf(v1.x); r.u[5] = f2bf(v1.y); r.u[6] = f2bf(v1.z); r.u[7] = f2bf(v1.w);
    *(uint4*)(dst + i) = r.q;
  }
}

// ---- prep kernel 2: W [K][O] f32 -> Wt [O][K] bf16, 64x64 tiles ----
__global__ __launch_bounds__(256) void k_transpose_w(
    const float* __restrict__ W, unsigned short* __restrict__ Wt) {
  __shared__ float tile[64][65];
  int o0 = blockIdx.x * 64;
  int k0 = blockIdx.y * 64;
  int t = threadIdx.x;
  int kr0 = t >> 4, c4 = t & 15;
#pragma unroll
  for (int i = 0; i < 4; i++) {
    int kr = kr0 + i * 16;
    float4 v = *(const float4*)&W[(size_t)(k0 + kr) * N_TOT + o0 + c4 * 4];
    tile[kr][c4 * 4 + 0] = v.x;
    tile[kr][c4 * 4 + 1] = v.y;
    tile[kr][c4 * 4 + 2] = v.z;
    tile[kr][c4 * 4 + 3] = v.w;
  }
  __syncthreads();
  int or0 = t >> 3, c8 = t & 7;
#pragma unroll
  for (int i = 0; i < 2; i++) {
    int orr = or0 + i * 32;
    union { unsigned short u[8]; uint4 q; } r;
#pragma unroll
    for (int j = 0; j < 8; j++) r.u[j] = f2bf(tile[c8 * 8 + j][orr]);
    *(uint4*)&Wt[(size_t)(o0 + orr) * K_TOT + k0 + c8 * 8] = r.q;
  }
}

// ---- prep kernel 3: sin/cos tables [row=8192][d=32] ----
__global__ __launch_bounds__(256) void k_sincos(
    const float* __restrict__ mass, float* __restrict__ sin_t, float* __restrict__ cos_t) {
  int t = blockIdx.x * 256 + threadIdx.x;   // 0..262143
  int row = t >> 5;
  int d = t & 31;
  float m = mass[row];
  float invf = expf(-0.28782313662425575f * (float)d);  // ln(10000)/32
  float ang = m * invf;
  float s, c;
  sincosf(ang, &s, &c);
  sin_t[t] = s;
  cos_t[t] = c;
}

// ---- main GEMM: 256x128 tile, BK=32, 4 waves (2x2), 3-deep pipelined LDS,
//      2 blocks/CU, conflict-free LDS swizzle (T2), L2 superblock swizzle,
//      REGISTER READ-AHEAD with race-safe ordering: every iter does
//      vmcnt(0) BEFORE the barrier (per-wave waits own staging loads ->
//      barrier makes the cooperative tile resident for ALL waves), then
//      STAGE(s+2), then a47(s) JIT reads + read-ahead(s+1) interleave
//      with the 32 MFMAs. Drained loads are 1 iter old (near-free). ----
__global__ __launch_bounds__(256, 2) void k_gemm256b(
    const unsigned short* __restrict__ A,    // [8192][1024] bf16
    const unsigned short* __restrict__ Bt,   // [16384][1024] bf16 (W^T)
    const float* __restrict__ bias,          // [16384]
    const float* __restrict__ sin_t,         // [8192][32]
    const float* __restrict__ cos_t,
    float* __restrict__ out)                 // [2][4][128][2048][64]
{
  extern __shared__ char smem[];   // 3 bufs x (As 16KB + Bs 8KB) = 72 KiB

  int tid  = threadIdx.x;
  int lane = tid & 63;
  int wid  = tid >> 6;      // 0..3
  int wm   = wid >> 1;      // 0..1  (M half: 128 rows)
  int wn   = wid & 1;       // 0..1  (N half: 64 cols)

  // L2-locality superblock swizzle (bijective; 4096 blocks):
  // XCD x owns 4 bm panels; bn walked in super-tiles of 4bm x 8bn.
  int orig = blockIdx.x;
  int x   = orig & 7;
  int c   = orig >> 3;
  int st  = c >> 5;
  int w   = c & 31;
  int bm0 = (x * 4 + (w >> 3)) * 256;    // bm index: 4x + 0..3   (32 total)
  int bn0 = (st * 8 + (w & 7)) * 128;    // bn index: 8*st + 0..7 (128 total)

  // staging with inverse-swizzled source (T2 both-sides, rule #21):
  int sv   = (tid & 7) ^ ((tid >> 3) & 7);
  int arow = ((tid >> 3) << 1) + (sv >> 2);
  int kst  = sv & 3;
  const unsigned short* srcA = A  + (size_t)(bm0 + arow) * K_TOT + kst * 8;
  const unsigned short* srcB = Bt + (size_t)(bn0 + arow) * K_TOT + kst * 8;
  const size_t rs64 = (size_t)64 * K_TOT;

  // wave-uniform LDS staging bases: A at buf+0 (16KB), B at buf+16384 (8KB)
  int wofs = wid * 1024;

#define STAGE_A(s_, bo_) do { char* dA = smem + (bo_) + wofs; \
    const unsigned short* sa = srcA + (size_t)(s_) * 32; \
    gload_lds16(sa,            dA); \
    gload_lds16(sa + rs64,     dA + 4096); \
    gload_lds16(sa + 2 * rs64, dA + 8192); \
    gload_lds16(sa + 3 * rs64, dA + 12288); } while (0)
#define STAGE_B(s_, bo_) do { char* dB = smem + (bo_) + 16384 + wofs; \
    const unsigned short* sb = srcB + (size_t)(s_) * 32; \
    gload_lds16(sb,        dB); \
    gload_lds16(sb + rs64, dB + 4096); } while (0)

  f32x4 acc[8][4] = {};

  int r = lane & 15;        // frag row/col within 16
  int q = lane >> 4;        // k-chunk 0..3 (8 bf16 each)
  // swizzled read offsets (conflict-free; matches staging permutation):
  int sl   = (((r & 1) << 2) + q) ^ ((r >> 1) & 7);
  int aoff = wm * 8192 + (r >> 1) * 128 + sl * 16;   // byte offset in As
  int boff = wn * 4096 + (r >> 1) * 128 + sl * 16;   // byte offset in Bs

  // prologue: stage tiles 0,1; wait OWN tile-0 loads; barrier (tile 0 now
  // resident across all waves); read tile 0's B + A03 frags.
  STAGE_A(0, 0); STAGE_B(0, 0);
  STAGE_A(1, 24576); STAGE_B(1, 24576);
  asm volatile("s_waitcnt vmcnt(6)" ::: "memory");   // own tile-0 loads done
  __builtin_amdgcn_s_barrier();                      // ALL waves' tile 0 done
  __builtin_amdgcn_sched_barrier(0);

  bf16x8 bX[4], aX[4], bY[4], aY[4];
#pragma unroll
  for (int ni = 0; ni < 4; ni++) bX[ni] = *(const bf16x8*)(smem + 16384 + boff + ni * 1024);
#pragma unroll
  for (int mi = 0; mi < 4; mi++) aX[mi] = *(const bf16x8*)(smem + aoff + mi * 1024);

  int cur = 0, nxt = 24576, stg = 49152;   // buf byte offsets: s%3, (s+1)%3, (s+2)%3

  // per-iter: vmcnt(0) [own tile s+1 loads done] -> barrier [tile s+1
  // resident for ALL waves] -> STAGE(s+2) -> a47(s) + read-ahead(s+1)
  // -> 32 MFMA (compiler interleaves the independent ds_reads).
#define GEMM_ITER(s_, BC, A03C, BN, A03N) do {                                  \
    asm volatile("s_waitcnt vmcnt(0)" ::: "memory");                            \
    __builtin_amdgcn_s_barrier();                                               \
    __builtin_amdgcn_sched_barrier(0);                                          \
    if ((s_) < 30) { STAGE_A((s_) + 2, stg); STAGE_B((s_) + 2, stg); }          \
    const char* As_ = smem + cur;                                               \
    const char* Asn = smem + nxt;                                               \
    bf16x8 a47[4];                                                              \
    _Pragma("unroll")                                                           \
    for (int mi = 0; mi < 4; mi++)                                              \
      a47[mi] = *(const bf16x8*)(As_ + aoff + (mi + 4) * 1024);                 \
    if ((s_) < 31) {                                                            \
      _Pragma("unroll")                                                         \
      for (int ni = 0; ni < 4; ni++)                                            \
        BN[ni] = *(const bf16x8*)(Asn + 16384 + boff + ni * 1024);              \
      _Pragma("unroll")                                                         \
      for (int mi = 0; mi < 4; mi++)                                            \
        A03N[mi] = *(const bf16x8*)(Asn + aoff + mi * 1024);                    \
    }                                                                           \
    __builtin_amdgcn_s_setprio(1);                                              \
    _Pragma("unroll")                                                           \
    for (int mi = 0; mi < 4; mi++)                                              \
      _Pragma("unroll")                                                         \
      for (int ni = 0; ni < 4; ni++)                                            \
        acc[mi][ni] = __builtin_amdgcn_mfma_f32_16x16x32_bf16(                  \
            A03C[mi], BC[ni], acc[mi][ni], 0, 0, 0);                            \
    _Pragma("unroll")                                                           \
    for (int mi = 0; mi < 4; mi++)                                              \
      _Pragma("unroll")                                                         \
      for (int ni = 0; ni < 4; ni++)                                            \
        acc[mi + 4][ni] = __builtin_amdgcn_mfma_f32_16x16x32_bf16(              \
            a47[mi], BC[ni], acc[mi + 4][ni], 0, 0, 0);                         \
    __builtin_amdgcn_s_setprio(0);                                              \
    int t_ = cur; cur = nxt; nxt = stg; stg = t_;                               \
  } while (0)

  for (int s2 = 0; s2 < 32; s2 += 2) {
    GEMM_ITER(s2,     bX, aX, bY, aY);
    GEMM_ITER(s2 + 1, bY, aY, bX, aX);
  }
#undef GEMM_ITER
#undef STAGE_A
#undef STAGE_B

  // ---- fused epilogue: bias + RoPE (K half) + transposed scatter ----
  int col16 = r;
  float bv[4];
#pragma unroll
  for (int ni = 0; ni < 4; ni++) bv[ni] = bias[bn0 + wn * 64 + ni * 16 + col16];

  int cgrp = (bn0 >> 6) + wn;          // head-channel index 0..255, wave-uniform
  int is_k = (cgrp < 128);
  int h = cgrp & 127;
  size_t sec = is_k ? 0 : 4;           // s*4 (s=0 for K, 1 for V)

#pragma unroll
  for (int mi = 0; mi < 8; mi++) {
#pragma unroll
    for (int reg = 0; reg < 4; reg++) {
      int row = bm0 + wm * 128 + mi * 16 + q * 4 + reg;
      int bb = row >> 11;
      int n  = row & 2047;
      float* op = out + (((sec + bb) * 128 + h) * 2048 + (size_t)n) * 64;
      if (is_k) {
#pragma unroll
        for (int ni = 0; ni < 2; ni++) {
          int d = ni * 16 + col16;               // d in [0,32)
          float x0 = acc[mi][ni][reg]     + bv[ni];
          float x1 = acc[mi][ni + 2][reg] + bv[ni + 2];
          float sv2 = sin_t[row * 32 + d];
          float cv2 = cos_t[row * 32 + d];
          op[d]      = x0 * cv2 - x1 * sv2;
          op[d + 32] = x0 * sv2 + x1 * cv2;
        }
      } else {
#pragma unroll
        for (int ni = 0; ni < 4; ni++) {
          int d = ni * 16 + col16;
          op[d] = acc[mi][ni][reg] + bv[ni];
        }
      }
    }
  }
}

extern "C" void kernel_launch(void* const* d_in, const int* in_sizes, int n_in,
                              void* d_out, int out_size, void* d_ws, size_t ws_size,
                              hipStream_t stream) {
  const float* node = (const float*)d_in[0];   // [4][2048][1024]
  const float* mass = (const float*)d_in[1];   // [4][2048]
  const float* W    = (const float*)d_in[2];   // [1024][16384]
  const float* bias = (const float*)d_in[3];   // [16384]
  float* out = (float*)d_out;

  // workspace layout
  const size_t NODE_B  = (size_t)M_TOT * K_TOT * 2;       // 16.78 MB
  const size_t WT_B    = (size_t)N_TOT * K_TOT * 2;       // 33.55 MB
  const size_t SIN_B   = (size_t)M_TOT * 32 * 4;          // 1.05 MB
  if (ws_size < NODE_B + WT_B + 2 * SIN_B) return;        // fail visibly

  char* ws = (char*)d_ws;
  unsigned short* nodeB = (unsigned short*)ws;
  unsigned short* WtB   = (unsigned short*)(ws + NODE_B);
  float* sin_t = (float*)(ws + NODE_B + WT_B);
  float* cos_t = (float*)(ws + NODE_B + WT_B + SIN_B);

  // allow 72 KiB dynamic LDS for the GEMM (2 blocks/CU: 2 x 72 <= 160 KiB)
  (void)hipFuncSetAttribute((const void*)k_gemm256b,
                            hipFuncAttributeMaxDynamicSharedMemorySize, 73728);

  k_convert_node<<<1024, 256, 0, stream>>>(node, nodeB);
  k_transpose_w<<<dim3(N_TOT / 64, K_TOT / 64), 256, 0, stream>>>(W, WtB);
  k_sincos<<<(M_TOT * 32) / 256, 256, 0, stream>>>(mass, sin_t, cos_t);
  k_gemm256b<<<dim3((M_TOT / 256) * (N_TOT / 128)), dim3(256), 73728, stream>>>(
      nodeB, WtB, bias, sin_t, cos_t, out);
}

// Round 15
// 360.893 us; speedup vs baseline: 1.0222x; 1.0222x over previous
//
#include <hip/hip_runtime.h>
#include <stdint.h>

// Problem constants
#define M_TOT 8192      // B*N = 4*2048 rows
#define N_TOT 16384     // out_dim = 2*128*64
#define K_TOT 1024      // HIDDEN

typedef __bf16 bf16x8 __attribute__((ext_vector_type(8)));
typedef float f32x4 __attribute__((ext_vector_type(4)));

__device__ __forceinline__ unsigned short f2bf(float f) {
  unsigned int u = __float_as_uint(f);
  u = u + 0x7FFFu + ((u >> 16) & 1u);   // RNE
  return (unsigned short)(u >> 16);
}

__device__ __forceinline__ void gload_lds16(const void* g, void* l) {
  __builtin_amdgcn_global_load_lds(
      (const __attribute__((address_space(1))) unsigned int*)g,
      (__attribute__((address_space(3))) unsigned int*)l,
      16, 0, 0);
}

// ---- prep kernel 1: node f32 -> bf16, 32 elems/thread, 1024 blocks ----
__global__ __launch_bounds__(256) void k_convert_node(
    const float* __restrict__ src, unsigned short* __restrict__ dst) {
  size_t base = ((size_t)blockIdx.x * 256 + threadIdx.x) * 8;
#pragma unroll
  for (int it = 0; it < 4; it++) {
    size_t i = base + (size_t)it * (1024 * 256 * 8);
    float4 v0 = *(const float4*)(src + i);
    float4 v1 = *(const float4*)(src + i + 4);
    union { unsigned short u[8]; uint4 q; } r;
    r.u[0] = f2bf(v0.x); r.u[1] = f2bf(v0.y); r.u[2] = f2bf(v0.z); r.u[3] = f2bf(v0.w);
    r.u[4] = f2bf(v1.x); r.u[5] = f2bf(v1.y); r.u[6] = f2bf(v1.z); r.u[7] = f2bf(v1.w);
    *(uint4*)(dst + i) = r.q;
  }
}

// ---- prep kernel 2: W [K][O] f32 -> Wt [O][K] bf16, 64x64 tiles ----
__global__ __launch_bounds__(256) void k_transpose_w(
    const float* __restrict__ W, unsigned short* __restrict__ Wt) {
  __shared__ float tile[64][65];
  int o0 = blockIdx.x * 64;
  int k0 = blockIdx.y * 64;
  int t = threadIdx.x;
  int kr0 = t >> 4, c4 = t & 15;
#pragma unroll
  for (int i = 0; i < 4; i++) {
    int kr = kr0 + i * 16;
    float4 v = *(const float4*)&W[(size_t)(k0 + kr) * N_TOT + o0 + c4 * 4];
    tile[kr][c4 * 4 + 0] = v.x;
    tile[kr][c4 * 4 + 1] = v.y;
    tile[kr][c4 * 4 + 2] = v.z;
    tile[kr][c4 * 4 + 3] = v.w;
  }
  __syncthreads();
  int or0 = t >> 3, c8 = t & 7;
#pragma unroll
  for (int i = 0; i < 2; i++) {
    int orr = or0 + i * 32;
    union { unsigned short u[8]; uint4 q; } r;
#pragma unroll
    for (int j = 0; j < 8; j++) r.u[j] = f2bf(tile[c8 * 8 + j][orr]);
    *(uint4*)&Wt[(size_t)(o0 + orr) * K_TOT + k0 + c8 * 8] = r.q;
  }
}

// ---- prep kernel 3: sin/cos tables [row=8192][d=32] ----
__global__ __launch_bounds__(256) void k_sincos(
    const float* __restrict__ mass, float* __restrict__ sin_t, float* __restrict__ cos_t) {
  int t = blockIdx.x * 256 + threadIdx.x;   // 0..262143
  int row = t >> 5;
  int d = t & 31;
  float m = mass[row];
  float invf = expf(-0.28782313662425575f * (float)d);  // ln(10000)/32
  float ang = m * invf;
  float s, c;
  sincosf(ang, &s, &c);
  sin_t[t] = s;
  cos_t[t] = c;
}

// ---- main GEMM: 256x256 tile, BK=64, 8 waves (2Mx4N), 8-phase schedule
//      (m201-style): per K-tile 4 phases of {stage 1 unit || ds_reads ->
//      barrier -> lgkmcnt(0) -> setprio(1) 16 MFMA setprio(0) -> barrier},
//      counted vmcnt(8) per phase (loads span >=5 phases, never drained
//      fresh in the main loop), derived vmcnt(4/2/0) in the peel.
//      LDS: 2 x 64 KiB dbuf; A stored as 2 M-quadrant units (swizzle
//      slot^row&7 on 128B rows), B as 2 K-half units (kh-major, 64B rows,
//      swizzle q^row&3). Sources pre-permuted, gload dest linear (T2
//      both-sides). L2 superblock XCD swizzle. ----
__global__ __launch_bounds__(512, 1) void k_gemm256c(
    const unsigned short* __restrict__ A,    // [8192][1024] bf16
    const unsigned short* __restrict__ Bt,   // [16384][1024] bf16 (W^T)
    const float* __restrict__ bias,          // [16384]
    const float* __restrict__ sin_t,         // [8192][32]
    const float* __restrict__ cos_t,
    float* __restrict__ out)                 // [2][4][128][2048][64]
{
  extern __shared__ char smem[];   // 2 x (UA0 16K | UA1 16K | UB0 16K | UB1 16K)

  int tid  = threadIdx.x;
  int lane = tid & 63;
  int wid  = tid >> 6;      // 0..7
  int wm   = wid >> 2;      // 0..1  (M half: 128 rows)
  int wn   = wid & 3;       // 0..3  (N quarter: 64 cols)

  // L2-locality superblock swizzle (bijective; 2048 blocks, %8==0):
  // XCD x owns bm 4x..4x+3 (A slice 2MB, L2-resident); 4bm x 4bn supertiles.
  int orig = blockIdx.x;
  int x  = orig & 7;
  int cc = orig >> 3;            // 0..255
  int st = cc >> 4;              // 16 super-tiles
  int w  = cc & 15;
  int bm0 = (x * 4 + (w >> 2)) * 256;   // 32 bm panels
  int bn0 = (st * 4 + (w & 3)) * 256;   // 64 bn panels

  // staging sources, pre-permuted for the LDS swizzles (rule #21):
  // A: unit chunk c=j*512+tid -> row_local=c>>3, dest slot=c&7,
  //    logical s = (tid&7)^((tid>>3)&7)  (row_local&7 == (tid>>3)&7)
  int rowA = tid >> 3;                       // 0..63
  int sA   = (tid & 7) ^ (rowA & 7);
  const unsigned short* gA = A + (size_t)(bm0 + rowA) * K_TOT + sA * 8;
  // B: chunk c=j*512+tid -> row=c>>2, dest slot4=c&3, q_src=(tid&3)^(row&3)
  int rowB = tid >> 2;                       // 0..127
  int qB   = (tid & 3) ^ (rowB & 3);
  const unsigned short* gB = Bt + (size_t)(bn0 + rowB) * K_TOT + qB * 8;

  int wofs = wid * 1024;

  // UA(mq) = A rows {mq*64..+64, 128+mq*64..+64}, full BK (16 KB)
#define STG_A(t_, mq) do { \
    char* d_ = smem + ((t_) & 1) * 65536 + (mq) * 16384 + wofs;            \
    const unsigned short* s_ = gA + (size_t)((mq) * 64) * K_TOT + (t_) * 64; \
    gload_lds16(s_, d_);                                                     \
    gload_lds16(s_ + (size_t)128 * K_TOT, d_ + 8192); } while (0)
  // UB(kh) = B rows 0..255, k-half kh (16 KB, kh-major)
#define STG_B(t_, kh) do { \
    char* d_ = smem + ((t_) & 1) * 65536 + 32768 + (kh) * 16384 + wofs;    \
    const unsigned short* s_ = gB + (t_) * 64 + (kh) * 32;                   \
    gload_lds16(s_, d_);                                                     \
    gload_lds16(s_ + (size_t)128 * K_TOT, d_ + 8192); } while (0)

  f32x4 acc[8][4] = {};
  bf16x8 bK[4], aF[4];

  int r = lane & 15;        // frag row/col within 16
  int q = lane >> 4;        // k-chunk 0..3
  // A read: unit mq, row_local = wm*64 + (mi&3)*16 + r, slot (kh*4+q)^(r&7)
  int aOff = (wm * 64 + r) * 128;
  int ks0  = ((q)     ^ (r & 7)) * 16;     // kh=0 slot byte
  int ks1  = ((4 + q) ^ (r & 7)) * 16;     // kh=1 slot byte
  // B read: UB(kh) @ 32768+kh*16384, row = wn*64 + ni*16 + r, slot q^(r&3)
  int bOff = 32768 + (wn * 64 + r) * 64 + ((q ^ (r & 3)) * 16);

#define RD_B(db_, kh) { _Pragma("unroll") \
    for (int ni = 0; ni < 4; ni++) \
      bK[ni] = *(const bf16x8*)((db_) + bOff + (kh) * 16384 + ni * 1024); }
#define RD_A(db_, mq, ks_) { _Pragma("unroll") \
    for (int i = 0; i < 4; i++) \
      aF[i] = *(const bf16x8*)((db_) + (mq) * 16384 + aOff + i * 2048 + (ks_)); }
#define MF_LO { _Pragma("unroll") for (int mi = 0; mi < 4; mi++) \
    _Pragma("unroll") for (int ni = 0; ni < 4; ni++) \
      acc[mi][ni] = __builtin_amdgcn_mfma_f32_16x16x32_bf16(aF[mi], bK[ni], acc[mi][ni], 0, 0, 0); }
#define MF_HI { _Pragma("unroll") for (int mi = 0; mi < 4; mi++) \
    _Pragma("unroll") for (int ni = 0; ni < 4; ni++) \
      acc[mi + 4][ni] = __builtin_amdgcn_mfma_f32_16x16x32_bf16(aF[mi], bK[ni], acc[mi + 4][ni], 0, 0, 0); }

#define W8 asm volatile("s_waitcnt vmcnt(8)" ::: "memory")
#define W4 asm volatile("s_waitcnt vmcnt(4)" ::: "memory")
#define W2 asm volatile("s_waitcnt vmcnt(2)" ::: "memory")
#define W0 asm volatile("s_waitcnt vmcnt(0)" ::: "memory")
#define BAR1 do { __builtin_amdgcn_s_barrier(); \
    asm volatile("s_waitcnt lgkmcnt(0)" ::: "memory"); \
    __builtin_amdgcn_sched_barrier(0); \
    __builtin_amdgcn_s_setprio(1); } while (0)
#define BAR2 do { __builtin_amdgcn_s_setprio(0); \
    __builtin_amdgcn_s_barrier(); \
    __builtin_amdgcn_sched_barrier(0); } while (0)

  // ---- prologue: tile0 all 4 units, tile1 UB0+UA0 (12 loads). vmcnt(8)
  //      forces the 2 oldest units = UB0(0), UA0(0) -> P0(0) readable. ----
  STG_B(0, 0); STG_A(0, 0); STG_A(0, 1); STG_B(0, 1);
  STG_B(1, 0); STG_A(1, 0);
  W8;
  __builtin_amdgcn_s_barrier();
  __builtin_amdgcn_sched_barrier(0);

  // ---- main loop, tiles 0..13 (steady state) ----
  // stage map: P0: UA1(t+1) | P1: UB1(t+1) | P2: UB0(t+2) | P3: UA0(t+2)
  // first-read distances all >=5 phases; vmcnt(8) invariant: after phase g's
  // wait, everything staged <= g-4 is complete.
  for (int t = 0; t < 14; t++) {
    const char* db = smem + (t & 1) * 65536;
    STG_A(t + 1, 1); RD_B(db, 0); RD_A(db, 0, ks0); W8; BAR1; MF_LO; BAR2;
    STG_B(t + 1, 1); RD_A(db, 1, ks0);              W8; BAR1; MF_HI; BAR2;
    STG_B(t + 2, 0); RD_B(db, 1); RD_A(db, 0, ks1); W8; BAR1; MF_LO; BAR2;
    STG_A(t + 2, 0); RD_A(db, 1, ks1);              W8; BAR1; MF_HI; BAR2;
  }
  // ---- tile 14: stop staging t+2; P3 wait derived vmcnt(4) ----
  {
    const char* db = smem;                 // 14 & 1 == 0
    STG_A(15, 1); RD_B(db, 0); RD_A(db, 0, ks0); W8; BAR1; MF_LO; BAR2;
    STG_B(15, 1); RD_A(db, 1, ks0);              W8; BAR1; MF_HI; BAR2;
                  RD_B(db, 1); RD_A(db, 0, ks1); W8; BAR1; MF_LO; BAR2;
                  RD_A(db, 1, ks1);              W4; BAR1; MF_HI; BAR2;
  }
  // ---- tile 15: derived waits vmcnt(2), vmcnt(0), none, none ----
  {
    const char* db = smem + 65536;
    RD_B(db, 0); RD_A(db, 0, ks0); W2; BAR1; MF_LO; BAR2;
    RD_A(db, 1, ks0);              W0; BAR1; MF_HI; BAR2;
    RD_B(db, 1); RD_A(db, 0, ks1);     BAR1; MF_LO; BAR2;
    RD_A(db, 1, ks1);                  BAR1; MF_HI; BAR2;
  }
#undef STG_A
#undef STG_B
#undef RD_B
#undef RD_A
#undef MF_LO
#undef MF_HI
#undef W8
#undef W4
#undef W2
#undef W0
#undef BAR1
#undef BAR2

  // ---- fused epilogue: bias + RoPE (K half) + transposed scatter ----
  int col16 = r;
  float bv[4];
#pragma unroll
  for (int ni = 0; ni < 4; ni++) bv[ni] = bias[bn0 + wn * 64 + ni * 16 + col16];

  int cgrp = (bn0 >> 6) + wn;          // head-channel index 0..255, wave-uniform
  int is_k = (cgrp < 128);
  int h = cgrp & 127;
  size_t sec = is_k ? 0 : 4;           // s*4 (s=0 for K, 1 for V)

#pragma unroll
  for (int mi = 0; mi < 8; mi++) {
#pragma unroll
    for (int reg = 0; reg < 4; reg++) {
      int row = bm0 + wm * 128 + mi * 16 + q * 4 + reg;
      int bb = row >> 11;
      int n  = row & 2047;
      float* op = out + (((sec + bb) * 128 + h) * 2048 + (size_t)n) * 64;
      if (is_k) {
#pragma unroll
        for (int ni = 0; ni < 2; ni++) {
          int d = ni * 16 + col16;               // d in [0,32)
          float x0 = acc[mi][ni][reg]     + bv[ni];
          float x1 = acc[mi][ni + 2][reg] + bv[ni + 2];
          float sv2 = sin_t[row * 32 + d];
          float cv2 = cos_t[row * 32 + d];
          op[d]      = x0 * cv2 - x1 * sv2;
          op[d + 32] = x0 * sv2 + x1 * cv2;
        }
      } else {
#pragma unroll
        for (int ni = 0; ni < 4; ni++) {
          int d = ni * 16 + col16;
          op[d] = acc[mi][ni][reg] + bv[ni];
        }
      }
    }
  }
}

extern "C" void kernel_launch(void* const* d_in, const int* in_sizes, int n_in,
                              void* d_out, int out_size, void* d_ws, size_t ws_size,
                              hipStream_t stream) {
  const float* node = (const float*)d_in[0];   // [4][2048][1024]
  const float* mass = (const float*)d_in[1];   // [4][2048]
  const float* W    = (const float*)d_in[2];   // [1024][16384]
  const float* bias = (const float*)d_in[3];   // [16384]
  float* out = (float*)d_out;

  // workspace layout
  const size_t NODE_B  = (size_t)M_TOT * K_TOT * 2;       // 16.78 MB
  const size_t WT_B    = (size_t)N_TOT * K_TOT * 2;       // 33.55 MB
  const size_t SIN_B   = (size_t)M_TOT * 32 * 4;          // 1.05 MB
  if (ws_size < NODE_B + WT_B + 2 * SIN_B) return;        // fail visibly

  char* ws = (char*)d_ws;
  unsigned short* nodeB = (unsigned short*)ws;
  unsigned short* WtB   = (unsigned short*)(ws + NODE_B);
  float* sin_t = (float*)(ws + NODE_B + WT_B);
  float* cos_t = (float*)(ws + NODE_B + WT_B + SIN_B);

  // 128 KiB dynamic LDS for the 8-phase GEMM (1 block/CU)
  (void)hipFuncSetAttribute((const void*)k_gemm256c,
                            hipFuncAttributeMaxDynamicSharedMemorySize, 131072);

  k_convert_node<<<1024, 256, 0, stream>>>(node, nodeB);
  k_transpose_w<<<dim3(N_TOT / 64, K_TOT / 64), 256, 0, stream>>>(W, WtB);
  k_sincos<<<(M_TOT * 32) / 256, 256, 0, stream>>>(mass, sin_t, cos_t);
  k_gemm256c<<<dim3((M_TOT / 256) * (N_TOT / 256)), dim3(512), 131072, stream>>>(
      nodeB, WtB, bias, sin_t, cos_t, out);
}

// Round 16
// 360.296 us; speedup vs baseline: 1.0239x; 1.0017x over previous
//
#include <hip/hip_runtime.h>
#include <stdint.h>

// Problem constants
#define M_TOT 8192      // B*N = 4*2048 rows
#define N_TOT 16384     // out_dim = 2*128*64
#define K_TOT 1024      // HIDDEN

typedef __bf16 bf16x8 __attribute__((ext_vector_type(8)));
typedef float f32x4 __attribute__((ext_vector_type(4)));

__device__ __forceinline__ unsigned short f2bf(float f) {
  unsigned int u = __float_as_uint(f);
  u = u + 0x7FFFu + ((u >> 16) & 1u);   // RNE
  return (unsigned short)(u >> 16);
}

__device__ __forceinline__ void gload_lds16(const void* g, void* l) {
  __builtin_amdgcn_global_load_lds(
      (const __attribute__((address_space(1))) unsigned int*)g,
      (__attribute__((address_space(3))) unsigned int*)l,
      16, 0, 0);
}

// ---- prep kernel 1: node f32 -> bf16, 32 elems/thread, 1024 blocks ----
__global__ __launch_bounds__(256) void k_convert_node(
    const float* __restrict__ src, unsigned short* __restrict__ dst) {
  size_t base = ((size_t)blockIdx.x * 256 + threadIdx.x) * 8;
#pragma unroll
  for (int it = 0; it < 4; it++) {
    size_t i = base + (size_t)it * (1024 * 256 * 8);
    float4 v0 = *(const float4*)(src + i);
    float4 v1 = *(const float4*)(src + i + 4);
    union { unsigned short u[8]; uint4 q; } r;
    r.u[0] = f2bf(v0.x); r.u[1] = f2bf(v0.y); r.u[2] = f2bf(v0.z); r.u[3] = f2bf(v0.w);
    r.u[4] = f2bf(v1.x); r.u[5] = f2bf(v1.y); r.u[6] = f2bf(v1.z); r.u[7] = f2bf(v1.w);
    *(uint4*)(dst + i) = r.q;
  }
}

// ---- prep kernel 2: W [K][O] f32 -> Wt [O][K] bf16, 64x64 tiles ----
__global__ __launch_bounds__(256) void k_transpose_w(
    const float* __restrict__ W, unsigned short* __restrict__ Wt) {
  __shared__ float tile[64][65];
  int o0 = blockIdx.x * 64;
  int k0 = blockIdx.y * 64;
  int t = threadIdx.x;
  int kr0 = t >> 4, c4 = t & 15;
#pragma unroll
  for (int i = 0; i < 4; i++) {
    int kr = kr0 + i * 16;
    float4 v = *(const float4*)&W[(size_t)(k0 + kr) * N_TOT + o0 + c4 * 4];
    tile[kr][c4 * 4 + 0] = v.x;
    tile[kr][c4 * 4 + 1] = v.y;
    tile[kr][c4 * 4 + 2] = v.z;
    tile[kr][c4 * 4 + 3] = v.w;
  }
  __syncthreads();
  int or0 = t >> 3, c8 = t & 7;
#pragma unroll
  for (int i = 0; i < 2; i++) {
    int orr = or0 + i * 32;
    union { unsigned short u[8]; uint4 q; } r;
#pragma unroll
    for (int j = 0; j < 8; j++) r.u[j] = f2bf(tile[c8 * 8 + j][orr]);
    *(uint4*)&Wt[(size_t)(o0 + orr) * K_TOT + k0 + c8 * 8] = r.q;
  }
}

// ---- prep kernel 3: sin/cos tables [row=8192][d=32] ----
__global__ __launch_bounds__(256) void k_sincos(
    const float* __restrict__ mass, float* __restrict__ sin_t, float* __restrict__ cos_t) {
  int t = blockIdx.x * 256 + threadIdx.x;   // 0..262143
  int row = t >> 5;
  int d = t & 31;
  float m = mass[row];
  float invf = expf(-0.28782313662425575f * (float)d);  // ln(10000)/32
  float ang = m * invf;
  float s, c;
  sincosf(ang, &s, &c);
  sin_t[t] = s;
  cos_t[t] = c;
}

// ---- main GEMM: 256x256 tile, BK=64, 8 waves (2Mx4N), 8-phase schedule,
//      counted vmcnt(8) (loads span >=5 phases), derived vmcnt(4/2/0) peel.
//      THIS ROUND: removed lgkmcnt(0) + all sched_barrier(0) from the phase
//      body (m141: order-pinning = -42%; compiler auto-inserts fine-grained
//      lgkmcnt before each MFMA, enabling read/MFMA overlap + cross-phase
//      pipelining). Phase = {STG || RD -> W8 -> barrier -> setprio MFMA -> barrier}.
//      LDS: 2 x 64 KiB dbuf; A as 2 M-quadrant units (slot^row&7, 128B rows),
//      B as 2 K-half units (kh-major, 64B rows, q^row&3). Sources pre-permuted,
//      gload dest linear (T2 both-sides). L2 superblock XCD swizzle. ----
__global__ __launch_bounds__(512, 1) void k_gemm256c(
    const unsigned short* __restrict__ A,    // [8192][1024] bf16
    const unsigned short* __restrict__ Bt,   // [16384][1024] bf16 (W^T)
    const float* __restrict__ bias,          // [16384]
    const float* __restrict__ sin_t,         // [8192][32]
    const float* __restrict__ cos_t,
    float* __restrict__ out)                 // [2][4][128][2048][64]
{
  extern __shared__ char smem[];   // 2 x (UA0 16K | UA1 16K | UB0 16K | UB1 16K)

  int tid  = threadIdx.x;
  int lane = tid & 63;
  int wid  = tid >> 6;      // 0..7
  int wm   = wid >> 2;      // 0..1  (M half: 128 rows)
  int wn   = wid & 3;       // 0..3  (N quarter: 64 cols)

  // L2-locality superblock swizzle (bijective; 2048 blocks, %8==0):
  int orig = blockIdx.x;
  int x  = orig & 7;
  int cc = orig >> 3;            // 0..255
  int st = cc >> 4;              // 16 super-tiles
  int w  = cc & 15;
  int bm0 = (x * 4 + (w >> 2)) * 256;   // 32 bm panels
  int bn0 = (st * 4 + (w & 3)) * 256;   // 64 bn panels

  // staging sources, pre-permuted for the LDS swizzles (rule #21):
  int rowA = tid >> 3;                       // 0..63
  int sA   = (tid & 7) ^ (rowA & 7);
  const unsigned short* gA = A + (size_t)(bm0 + rowA) * K_TOT + sA * 8;
  int rowB = tid >> 2;                       // 0..127
  int qB   = (tid & 3) ^ (rowB & 3);
  const unsigned short* gB = Bt + (size_t)(bn0 + rowB) * K_TOT + qB * 8;

  int wofs = wid * 1024;

  // UA(mq) = A rows {mq*64..+64, 128+mq*64..+64}, full BK (16 KB)
#define STG_A(t_, mq) do { \
    char* d_ = smem + ((t_) & 1) * 65536 + (mq) * 16384 + wofs;            \
    const unsigned short* s_ = gA + (size_t)((mq) * 64) * K_TOT + (t_) * 64; \
    gload_lds16(s_, d_);                                                     \
    gload_lds16(s_ + (size_t)128 * K_TOT, d_ + 8192); } while (0)
  // UB(kh) = B rows 0..255, k-half kh (16 KB, kh-major)
#define STG_B(t_, kh) do { \
    char* d_ = smem + ((t_) & 1) * 65536 + 32768 + (kh) * 16384 + wofs;    \
    const unsigned short* s_ = gB + (t_) * 64 + (kh) * 32;                   \
    gload_lds16(s_, d_);                                                     \
    gload_lds16(s_ + (size_t)128 * K_TOT, d_ + 8192); } while (0)

  f32x4 acc[8][4] = {};
  bf16x8 bK[4], aF[4];

  int r = lane & 15;        // frag row/col within 16
  int q = lane >> 4;        // k-chunk 0..3
  int aOff = (wm * 64 + r) * 128;
  int ks0  = ((q)     ^ (r & 7)) * 16;     // kh=0 slot byte
  int ks1  = ((4 + q) ^ (r & 7)) * 16;     // kh=1 slot byte
  int bOff = 32768 + (wn * 64 + r) * 64 + ((q ^ (r & 3)) * 16);

#define RD_B(db_, kh) { _Pragma("unroll") \
    for (int ni = 0; ni < 4; ni++) \
      bK[ni] = *(const bf16x8*)((db_) + bOff + (kh) * 16384 + ni * 1024); }
#define RD_A(db_, mq, ks_) { _Pragma("unroll") \
    for (int i = 0; i < 4; i++) \
      aF[i] = *(const bf16x8*)((db_) + (mq) * 16384 + aOff + i * 2048 + (ks_)); }
#define MF_LO { _Pragma("unroll") for (int mi = 0; mi < 4; mi++) \
    _Pragma("unroll") for (int ni = 0; ni < 4; ni++) \
      acc[mi][ni] = __builtin_amdgcn_mfma_f32_16x16x32_bf16(aF[mi], bK[ni], acc[mi][ni], 0, 0, 0); }
#define MF_HI { _Pragma("unroll") for (int mi = 0; mi < 4; mi++) \
    _Pragma("unroll") for (int ni = 0; ni < 4; ni++) \
      acc[mi + 4][ni] = __builtin_amdgcn_mfma_f32_16x16x32_bf16(aF[mi], bK[ni], acc[mi + 4][ni], 0, 0, 0); }

#define W8 asm volatile("s_waitcnt vmcnt(8)" ::: "memory")
#define W4 asm volatile("s_waitcnt vmcnt(4)" ::: "memory")
#define W2 asm volatile("s_waitcnt vmcnt(2)" ::: "memory")
#define W0 asm volatile("s_waitcnt vmcnt(0)" ::: "memory")
// No lgkmcnt(0), no sched_barrier: C++ ds_reads get compiler-inserted
// fine-grained lgkmcnt before each consuming MFMA (m97 asm evidence);
// pinning the order was the m141 anti-pattern.
#define BAR1 do { __builtin_amdgcn_s_barrier(); \
    __builtin_amdgcn_s_setprio(1); } while (0)
#define BAR2 do { __builtin_amdgcn_s_setprio(0); \
    __builtin_amdgcn_s_barrier(); } while (0)

  // ---- prologue: tile0 all 4 units, tile1 UB0+UA0 (12 loads). ----
  STG_B(0, 0); STG_A(0, 0); STG_A(0, 1); STG_B(0, 1);
  STG_B(1, 0); STG_A(1, 0);
  W8;
  __builtin_amdgcn_s_barrier();

  // ---- main loop, tiles 0..13 (steady state) ----
  // stage map: P0: UA1(t+1) | P1: UB1(t+1) | P2: UB0(t+2) | P3: UA0(t+2)
  // first-read distances all >=5 phases; vmcnt(8) invariant holds.
  for (int t = 0; t < 14; t++) {
    const char* db = smem + (t & 1) * 65536;
    STG_A(t + 1, 1); RD_B(db, 0); RD_A(db, 0, ks0); W8; BAR1; MF_LO; BAR2;
    STG_B(t + 1, 1); RD_A(db, 1, ks0);              W8; BAR1; MF_HI; BAR2;
    STG_B(t + 2, 0); RD_B(db, 1); RD_A(db, 0, ks1); W8; BAR1; MF_LO; BAR2;
    STG_A(t + 2, 0); RD_A(db, 1, ks1);              W8; BAR1; MF_HI; BAR2;
  }
  // ---- tile 14: stop staging t+2; P3 wait derived vmcnt(4) ----
  {
    const char* db = smem;                 // 14 & 1 == 0
    STG_A(15, 1); RD_B(db, 0); RD_A(db, 0, ks0); W8; BAR1; MF_LO; BAR2;
    STG_B(15, 1); RD_A(db, 1, ks0);              W8; BAR1; MF_HI; BAR2;
                  RD_B(db, 1); RD_A(db, 0, ks1); W8; BAR1; MF_LO; BAR2;
                  RD_A(db, 1, ks1);              W4; BAR1; MF_HI; BAR2;
  }
  // ---- tile 15: derived waits vmcnt(2), vmcnt(0), none, none ----
  {
    const char* db = smem + 65536;
    RD_B(db, 0); RD_A(db, 0, ks0); W2; BAR1; MF_LO; BAR2;
    RD_A(db, 1, ks0);              W0; BAR1; MF_HI; BAR2;
    RD_B(db, 1); RD_A(db, 0, ks1);     BAR1; MF_LO; BAR2;
    RD_A(db, 1, ks1);                  BAR1; MF_HI; BAR2;
  }
#undef STG_A
#undef STG_B
#undef RD_B
#undef RD_A
#undef MF_LO
#undef MF_HI
#undef W8
#undef W4
#undef W2
#undef W0
#undef BAR1
#undef BAR2

  // ---- fused epilogue: bias + RoPE (K half) + transposed scatter ----
  int col16 = r;
  float bv[4];
#pragma unroll
  for (int ni = 0; ni < 4; ni++) bv[ni] = bias[bn0 + wn * 64 + ni * 16 + col16];

  int cgrp = (bn0 >> 6) + wn;          // head-channel index 0..255, wave-uniform
  int is_k = (cgrp < 128);
  int h = cgrp & 127;
  size_t sec = is_k ? 0 : 4;           // s*4 (s=0 for K, 1 for V)

#pragma unroll
  for (int mi = 0; mi < 8; mi++) {
#pragma unroll
    for (int reg = 0; reg < 4; reg++) {
      int row = bm0 + wm * 128 + mi * 16 + q * 4 + reg;
      int bb = row >> 11;
      int n  = row & 2047;
      float* op = out + (((sec + bb) * 128 + h) * 2048 + (size_t)n) * 64;
      if (is_k) {
#pragma unroll
        for (int ni = 0; ni < 2; ni++) {
          int d = ni * 16 + col16;               // d in [0,32)
          float x0 = acc[mi][ni][reg]     + bv[ni];
          float x1 = acc[mi][ni + 2][reg] + bv[ni + 2];
          float sv2 = sin_t[row * 32 + d];
          float cv2 = cos_t[row * 32 + d];
          op[d]      = x0 * cv2 - x1 * sv2;
          op[d + 32] = x0 * sv2 + x1 * cv2;
        }
      } else {
#pragma unroll
        for (int ni = 0; ni < 4; ni++) {
          int d = ni * 16 + col16;
          op[d] = acc[mi][ni][reg] + bv[ni];
        }
      }
    }
  }
}

extern "C" void kernel_launch(void* const* d_in, const int* in_sizes, int n_in,
                              void* d_out, int out_size, void* d_ws, size_t ws_size,
                              hipStream_t stream) {
  const float* node = (const float*)d_in[0];   // [4][2048][1024]
  const float* mass = (const float*)d_in[1];   // [4][2048]
  const float* W    = (const float*)d_in[2];   // [1024][16384]
  const float* bias = (const float*)d_in[3];   // [16384]
  float* out = (float*)d_out;

  // workspace layout
  const size_t NODE_B  = (size_t)M_TOT * K_TOT * 2;       // 16.78 MB
  const size_t WT_B    = (size_t)N_TOT * K_TOT * 2;       // 33.55 MB
  const size_t SIN_B   = (size_t)M_TOT * 32 * 4;          // 1.05 MB
  if (ws_size < NODE_B + WT_B + 2 * SIN_B) return;        // fail visibly

  char* ws = (char*)d_ws;
  unsigned short* nodeB = (unsigned short*)ws;
  unsigned short* WtB   = (unsigned short*)(ws + NODE_B);
  float* sin_t = (float*)(ws + NODE_B + WT_B);
  float* cos_t = (float*)(ws + NODE_B + WT_B + SIN_B);

  // 128 KiB dynamic LDS for the 8-phase GEMM (1 block/CU)
  (void)hipFuncSetAttribute((const void*)k_gemm256c,
                            hipFuncAttributeMaxDynamicSharedMemorySize, 131072);

  k_convert_node<<<1024, 256, 0, stream>>>(node, nodeB);
  k_transpose_w<<<dim3(N_TOT / 64, K_TOT / 64), 256, 0, stream>>>(W, WtB);
  k_sincos<<<(M_TOT * 32) / 256, 256, 0, stream>>>(mass, sin_t, cos_t);
  k_gemm256c<<<dim3((M_TOT / 256) * (N_TOT / 256)), dim3(512), 131072, stream>>>(
      nodeB, WtB, bias, sin_t, cos_t, out);
}

// Round 17
// 326.048 us; speedup vs baseline: 1.1314x; 1.1050x over previous
//
#include <hip/hip_runtime.h>
#include <stdint.h>

// Problem constants
#define M_TOT 8192      // B*N = 4*2048 rows
#define N_TOT 16384     // out_dim = 2*128*64
#define K_TOT 1024      // HIDDEN

typedef __bf16 bf16x8 __attribute__((ext_vector_type(8)));
typedef float f32x4 __attribute__((ext_vector_type(4)));

__device__ __forceinline__ unsigned short f2bf(float f) {
  unsigned int u = __float_as_uint(f);
  u = u + 0x7FFFu + ((u >> 16) & 1u);   // RNE
  return (unsigned short)(u >> 16);
}

__device__ __forceinline__ void gload_lds16(const void* g, void* l) {
  __builtin_amdgcn_global_load_lds(
      (const __attribute__((address_space(1))) unsigned int*)g,
      (__attribute__((address_space(3))) unsigned int*)l,
      16, 0, 0);
}

// ---- prep kernel 1: node f32 -> bf16, 32 elems/thread, 1024 blocks ----
__global__ __launch_bounds__(256) void k_convert_node(
    const float* __restrict__ src, unsigned short* __restrict__ dst) {
  size_t base = ((size_t)blockIdx.x * 256 + threadIdx.x) * 8;
#pragma unroll
  for (int it = 0; it < 4; it++) {
    size_t i = base + (size_t)it * (1024 * 256 * 8);
    float4 v0 = *(const float4*)(src + i);
    float4 v1 = *(const float4*)(src + i + 4);
    union { unsigned short u[8]; uint4 q; } r;
    r.u[0] = f2bf(v0.x); r.u[1] = f2bf(v0.y); r.u[2] = f2bf(v0.z); r.u[3] = f2bf(v0.w);
    r.u[4] = f2bf(v1.x); r.u[5] = f2bf(v1.y); r.u[6] = f2bf(v1.z); r.u[7] = f2bf(v1.w);
    *(uint4*)(dst + i) = r.q;
  }
}

// ---- prep kernel 2: W [K][O] f32 -> Wt [O][K] bf16, 64x64 tiles ----
__global__ __launch_bounds__(256) void k_transpose_w(
    const float* __restrict__ W, unsigned short* __restrict__ Wt) {
  __shared__ float tile[64][65];
  int o0 = blockIdx.x * 64;
  int k0 = blockIdx.y * 64;
  int t = threadIdx.x;
  int kr0 = t >> 4, c4 = t & 15;
#pragma unroll
  for (int i = 0; i < 4; i++) {
    int kr = kr0 + i * 16;
    float4 v = *(const float4*)&W[(size_t)(k0 + kr) * N_TOT + o0 + c4 * 4];
    tile[kr][c4 * 4 + 0] = v.x;
    tile[kr][c4 * 4 + 1] = v.y;
    tile[kr][c4 * 4 + 2] = v.z;
    tile[kr][c4 * 4 + 3] = v.w;
  }
  __syncthreads();
  int or0 = t >> 3, c8 = t & 7;
#pragma unroll
  for (int i = 0; i < 2; i++) {
    int orr = or0 + i * 32;
    union { unsigned short u[8]; uint4 q; } r;
#pragma unroll
    for (int j = 0; j < 8; j++) r.u[j] = f2bf(tile[c8 * 8 + j][orr]);
    *(uint4*)&Wt[(size_t)(o0 + orr) * K_TOT + k0 + c8 * 8] = r.q;
  }
}

// ---- prep kernel 3: sin/cos tables [row=8192][d=32] ----
__global__ __launch_bounds__(256) void k_sincos(
    const float* __restrict__ mass, float* __restrict__ sin_t, float* __restrict__ cos_t) {
  int t = blockIdx.x * 256 + threadIdx.x;   // 0..262143
  int row = t >> 5;
  int d = t & 31;
  float m = mass[row];
  float invf = expf(-0.28782313662425575f * (float)d);  // ln(10000)/32
  float ang = m * invf;
  float s, c;
  sincosf(ang, &s, &c);
  sin_t[t] = s;
  cos_t[t] = c;
}

// ---- main GEMM: 256x128 tile, BK=32, 4 waves (2x2), 3-deep pipelined LDS,
//      counted vmcnt (T3+T4), 2 blocks/CU, conflict-free LDS swizzle (T2),
//      L2-locality superblock XCD swizzle, barrier-paired phases — the
//      best-measured structure (r7: 318 us GEMM).
//      THIS ROUND'S ONE CHANGE: epilogue stores are NONTEMPORAL (nt flag,
//      bypass L2/L3). The 524 MB f32 output is written once and never
//      re-read — caching it evicts the A/B panels (FETCH 254 MB vs 50 MB
//      unique) and slows staging loads, which no schedule depth can hide. ----
__global__ __launch_bounds__(256, 2) void k_gemm256b(
    const unsigned short* __restrict__ A,    // [8192][1024] bf16
    const unsigned short* __restrict__ Bt,   // [16384][1024] bf16 (W^T)
    const float* __restrict__ bias,          // [16384]
    const float* __restrict__ sin_t,         // [8192][32]
    const float* __restrict__ cos_t,
    float* __restrict__ out)                 // [2][4][128][2048][64]
{
  extern __shared__ char smem[];   // 3 bufs x (As 16KB + Bs 8KB) = 72 KiB

  int tid  = threadIdx.x;
  int lane = tid & 63;
  int wid  = tid >> 6;      // 0..3
  int wm   = wid >> 1;      // 0..1  (M half: 128 rows)
  int wn   = wid & 1;       // 0..1  (N half: 64 cols)

  // L2-locality superblock swizzle (bijective; 4096 blocks, 4096 % 8 == 0):
  // XCD x owns 4 bm panels; bn walked in super-tiles of 4bm x 8bn.
  int orig = blockIdx.x;
  int x   = orig & 7;
  int c   = orig >> 3;
  int st  = c >> 5;
  int w   = c & 31;
  int bm0 = (x * 4 + (w >> 3)) * 256;    // bm index: 4x + 0..3   (32 total)
  int bn0 = (st * 8 + (w & 7)) * 128;    // bn index: 8*st + 0..7 (128 total)

  // staging with inverse-swizzled source (T2 both-sides, rule #21):
  // chunk c = j*256 + tid: rowp = c>>3, s' = c&7, v = s' ^ (rowp&7),
  // row = (rowp<<1)+(v>>2), kslot = v&3.
  int sv   = (tid & 7) ^ ((tid >> 3) & 7);
  int arow = ((tid >> 3) << 1) + (sv >> 2);
  int kst  = sv & 3;
  const unsigned short* srcA = A  + (size_t)(bm0 + arow) * K_TOT + kst * 8;
  const unsigned short* srcB = Bt + (size_t)(bn0 + arow) * K_TOT + kst * 8;
  const size_t rs64 = (size_t)64 * K_TOT;

  // wave-uniform LDS staging bases: A at buf+0 (16KB), B at buf+16384 (8KB)
  int wofs = wid * 1024;

#define STAGE_A(s_, bo_) do { char* dA = smem + (bo_) + wofs; \
    const unsigned short* sa = srcA + (size_t)(s_) * 32; \
    gload_lds16(sa,            dA); \
    gload_lds16(sa + rs64,     dA + 4096); \
    gload_lds16(sa + 2 * rs64, dA + 8192); \
    gload_lds16(sa + 3 * rs64, dA + 12288); } while (0)
#define STAGE_B(s_, bo_) do { char* dB = smem + (bo_) + 16384 + wofs; \
    const unsigned short* sb = srcB + (size_t)(s_) * 32; \
    gload_lds16(sb,        dB); \
    gload_lds16(sb + rs64, dB + 4096); } while (0)

  // prologue: prefetch K-tiles 0,1 (12 loads in flight per wave)
  STAGE_A(0, 0); STAGE_B(0, 0);
  STAGE_A(1, 24576); STAGE_B(1, 24576);

  f32x4 acc[8][4] = {};

  int r = lane & 15;        // frag row/col within 16
  int q = lane >> 4;        // k-chunk 0..3 (8 bf16 each)
  // swizzled read offsets (conflict-free; matches staging permutation):
  int sl   = (((r & 1) << 2) + q) ^ ((r >> 1) & 7);
  int aoff = wm * 8192 + (r >> 1) * 128 + sl * 16;   // byte offset in As
  int boff = wn * 4096 + (r >> 1) * 128 + sl * 16;   // byte offset in Bs

  int cur = 0;              // buf byte offsets rotate 0 -> 24576 -> 49152
  int stg = 49152;          // stage target for tile s+2 = buf (s-1)%3

  for (int s = 0; s < 32; ++s) {
    if (s < 31) { asm volatile("s_waitcnt vmcnt(6)" ::: "memory"); }
    else        { asm volatile("s_waitcnt vmcnt(0)" ::: "memory"); }
    __builtin_amdgcn_s_barrier();          // tile s resident for ALL waves
    __builtin_amdgcn_sched_barrier(0);     // keep ds_reads below the barrier

    const char* As_ = smem + cur;
    const char* Bs_ = As_ + 16384;

    // ---- phase 0: {B frags + A frags (m 0..3), stage A(s+2)} -> barrier
    //      -> lgkmcnt(0) -> MFMA cluster ----
    bf16x8 bfrag[4], afrag[4];
#pragma unroll
    for (int ni = 0; ni < 4; ni++) bfrag[ni] = *(const bf16x8*)(Bs_ + boff + ni * 1024);
#pragma unroll
    for (int mi = 0; mi < 4; mi++) afrag[mi] = *(const bf16x8*)(As_ + aoff + mi * 1024);
    if (s < 30) STAGE_A(s + 2, stg);
    __builtin_amdgcn_sched_barrier(0);     // pin reads+stage above the barrier
    __builtin_amdgcn_s_barrier();
    asm volatile("s_waitcnt lgkmcnt(0)" ::: "memory");
    __builtin_amdgcn_sched_barrier(0);
    __builtin_amdgcn_s_setprio(1);
#pragma unroll
    for (int mi = 0; mi < 4; mi++)
#pragma unroll
      for (int ni = 0; ni < 4; ni++)
        acc[mi][ni] = __builtin_amdgcn_mfma_f32_16x16x32_bf16(afrag[mi], bfrag[ni], acc[mi][ni], 0, 0, 0);
    __builtin_amdgcn_s_setprio(0);

    // ---- phase 1: {A frags (m 4..7), stage B(s+2)} -> barrier
    //      -> lgkmcnt(0) -> MFMA cluster ----
    bf16x8 afrag2[4];
#pragma unroll
    for (int mi = 0; mi < 4; mi++) afrag2[mi] = *(const bf16x8*)(As_ + aoff + (mi + 4) * 1024);
    if (s < 30) STAGE_B(s + 2, stg);
    __builtin_amdgcn_sched_barrier(0);     // pin reads+stage above the barrier
    __builtin_amdgcn_s_barrier();
    asm volatile("s_waitcnt lgkmcnt(0)" ::: "memory");
    __builtin_amdgcn_sched_barrier(0);
    __builtin_amdgcn_s_setprio(1);
#pragma unroll
    for (int mi = 0; mi < 4; mi++)
#pragma unroll
      for (int ni = 0; ni < 4; ni++)
        acc[mi + 4][ni] = __builtin_amdgcn_mfma_f32_16x16x32_bf16(afrag2[mi], bfrag[ni], acc[mi + 4][ni], 0, 0, 0);
    __builtin_amdgcn_s_setprio(0);

    stg = cur;                                  // next stage target = buf we just read
    cur = (cur == 49152) ? 0 : cur + 24576;     // advance read buf
  }
#undef STAGE_A
#undef STAGE_B

  // ---- fused epilogue: bias + RoPE (K half) + transposed NONTEMPORAL
  //      scatter (nt stores bypass L2/L3 — output is never re-read) ----
  int col16 = r;
  float bv[4];
#pragma unroll
  for (int ni = 0; ni < 4; ni++) bv[ni] = bias[bn0 + wn * 64 + ni * 16 + col16];

  int cgrp = (bn0 >> 6) + wn;          // head-channel index 0..255, wave-uniform
  int is_k = (cgrp < 128);
  int h = cgrp & 127;
  size_t sec = is_k ? 0 : 4;           // s*4 (s=0 for K, 1 for V)

#pragma unroll
  for (int mi = 0; mi < 8; mi++) {
#pragma unroll
    for (int reg = 0; reg < 4; reg++) {
      int row = bm0 + wm * 128 + mi * 16 + q * 4 + reg;
      int bb = row >> 11;
      int n  = row & 2047;
      float* op = out + (((sec + bb) * 128 + h) * 2048 + (size_t)n) * 64;
      if (is_k) {
#pragma unroll
        for (int ni = 0; ni < 2; ni++) {
          int d = ni * 16 + col16;               // d in [0,32)
          float x0 = acc[mi][ni][reg]     + bv[ni];
          float x1 = acc[mi][ni + 2][reg] + bv[ni + 2];
          float sv2 = sin_t[row * 32 + d];
          float cv2 = cos_t[row * 32 + d];
          __builtin_nontemporal_store(x0 * cv2 - x1 * sv2, op + d);
          __builtin_nontemporal_store(x0 * sv2 + x1 * cv2, op + d + 32);
        }
      } else {
#pragma unroll
        for (int ni = 0; ni < 4; ni++) {
          int d = ni * 16 + col16;
          __builtin_nontemporal_store(acc[mi][ni][reg] + bv[ni], op + d);
        }
      }
    }
  }
}

extern "C" void kernel_launch(void* const* d_in, const int* in_sizes, int n_in,
                              void* d_out, int out_size, void* d_ws, size_t ws_size,
                              hipStream_t stream) {
  const float* node = (const float*)d_in[0];   // [4][2048][1024]
  const float* mass = (const float*)d_in[1];   // [4][2048]
  const float* W    = (const float*)d_in[2];   // [1024][16384]
  const float* bias = (const float*)d_in[3];   // [16384]
  float* out = (float*)d_out;

  // workspace layout
  const size_t NODE_B  = (size_t)M_TOT * K_TOT * 2;       // 16.78 MB
  const size_t WT_B    = (size_t)N_TOT * K_TOT * 2;       // 33.55 MB
  const size_t SIN_B   = (size_t)M_TOT * 32 * 4;          // 1.05 MB
  if (ws_size < NODE_B + WT_B + 2 * SIN_B) return;        // fail visibly

  char* ws = (char*)d_ws;
  unsigned short* nodeB = (unsigned short*)ws;
  unsigned short* WtB   = (unsigned short*)(ws + NODE_B);
  float* sin_t = (float*)(ws + NODE_B + WT_B);
  float* cos_t = (float*)(ws + NODE_B + WT_B + SIN_B);

  // allow 72 KiB dynamic LDS for the GEMM (2 blocks/CU: 2 x 72 <= 160 KiB)
  (void)hipFuncSetAttribute((const void*)k_gemm256b,
                            hipFuncAttributeMaxDynamicSharedMemorySize, 73728);

  k_convert_node<<<1024, 256, 0, stream>>>(node, nodeB);
  k_transpose_w<<<dim3(N_TOT / 64, K_TOT / 64), 256, 0, stream>>>(W, WtB);
  k_sincos<<<(M_TOT * 32) / 256, 256, 0, stream>>>(mass, sin_t, cos_t);
  k_gemm256b<<<dim3((M_TOT / 256) * (N_TOT / 128)), dim3(256), 73728, stream>>>(
      nodeB, WtB, bias, sin_t, cos_t, out);
}